// Round 5
// baseline (487.859 us; speedup 1.0000x reference)
//
#include <hip/hip_runtime.h>

#define SD 64   // STATE_DIM
#define MD 32   // MEASURE_DIM

typedef float f32x4 __attribute__((ext_vector_type(4)));
typedef float f32x2 __attribute__((ext_vector_type(2)));

// Static device storage for the prepare->apply handoff (d_ws unused; round-4
// proved the 1 GiB ws poison fill is unconditional, but g_Kt costs nothing).
// g_Kt[j*64+i] = K[i][j] (transposed: per-(wave,j) 16 consecutive floats ->
// one merged s_load in apply). g_b = b. Fully rewritten every launch.
__device__ float g_Kt[MD * SD];
__device__ float g_b[SD];

// ---------------------------------------------------------------------------
// Kernel A: one block, 1024 threads. Computes K [64x32] and b [64]:
//   x_new = b + K @ z,  b = x_pred - K @ (H @ x_pred)
// (verified rounds 0-4; only the output layout changed: K^T + b)
// ---------------------------------------------------------------------------
__global__ __launch_bounds__(1024) void akf_prepare(
    const float* __restrict__ F, const float* __restrict__ H,
    const float* __restrict__ Q, const float* __restrict__ R,
    const float* __restrict__ P, const float* __restrict__ x)
{
    __shared__ __align__(16) float sF [SD * SD];    // F row-major (broadcast reads)
    __shared__ __align__(16) float sFt[SD * 68];    // sFt[k*68+j] = F[j][k]
    __shared__ __align__(16) float sP [SD * SD];    // P row-major
    __shared__ __align__(16) float sT [SD * 68];    // T = F@P
    __shared__ __align__(16) float sPp[SD * 68];    // P_pred
    __shared__ __align__(16) float sH [MD * SD];    // H row-major (broadcast reads)
    __shared__ __align__(16) float sHt[SD * 36];    // sHt[k*36+j] = H[j][k]
    __shared__ __align__(16) float sA [SD * 36];    // A = P_pred @ H^T
    __shared__ __align__(16) float sS [MD * 33];    // S
    __shared__ __align__(16) float sSi[MD * 36];    // S^{-1}
    __shared__ __align__(16) float sK [SD * 36];    // K
    __shared__ float sx[SD], sxp[SD], sHx[MD];

    const int tid = threadIdx.x;

    // ---- stage inputs (coalesced reads; transposed copies for column access)
    for (int idx = tid; idx < SD * SD; idx += 1024) {
        float f = F[idx], p = P[idx];
        int i = idx >> 6, j = idx & 63;
        sF[idx] = f;
        sFt[j * 68 + i] = f;
        sP[idx] = p;
    }
    for (int idx = tid; idx < MD * SD; idx += 1024) {
        float h = H[idx];
        int j = idx >> 6, k = idx & 63;
        sH[idx] = h;
        sHt[k * 36 + j] = h;
    }
    if (tid < SD) sx[tid] = x[tid];
    __syncthreads();

    // ---- x_pred = F @ x  (column-major F reads via sFt: conflict-free)
    if (tid < SD) {
        float a = 0.f;
        for (int k = 0; k < SD; ++k) a = fmaf(sFt[k * 68 + tid], sx[k], a);
        sxp[tid] = a;
    }

    // ---- T = F @ P : thread -> (i, j0..j0+3)
    {
        const int i = tid >> 4, j0 = (tid & 15) * 4;
        f32x4 acc = {0.f, 0.f, 0.f, 0.f};
        for (int k = 0; k < SD; ++k) {
            const float f = sF[i * 64 + k];                     // wave broadcast
            const f32x4 p4 = *(const f32x4*)&sP[k * 64 + j0];   // b128, bank-spread
            acc.x = fmaf(f, p4.x, acc.x);
            acc.y = fmaf(f, p4.y, acc.y);
            acc.z = fmaf(f, p4.z, acc.z);
            acc.w = fmaf(f, p4.w, acc.w);
        }
        *(f32x4*)&sT[i * 68 + j0] = acc;
    }
    __syncthreads();

    // ---- P_pred = T @ F^T + Q
    {
        const int i = tid >> 4, j0 = (tid & 15) * 4;
        f32x4 acc = *(const f32x4*)&Q[i * 64 + j0];
        for (int k = 0; k < SD; ++k) {
            const float t = sT[i * 68 + k];
            const f32x4 f4 = *(const f32x4*)&sFt[k * 68 + j0];
            acc.x = fmaf(t, f4.x, acc.x);
            acc.y = fmaf(t, f4.y, acc.y);
            acc.z = fmaf(t, f4.z, acc.z);
            acc.w = fmaf(t, f4.w, acc.w);
        }
        *(f32x4*)&sPp[i * 68 + j0] = acc;
    }
    __syncthreads();

    // ---- Hx = H @ x_pred (tid<32) and A = P_pred @ H^T (tid<512)
    if (tid < MD) {
        float a = 0.f;
        for (int k = 0; k < SD; ++k) a = fmaf(sHt[k * 36 + tid], sxp[k], a);
        sHx[tid] = a;
    }
    if (tid < 512) {
        const int i = tid >> 3, j0 = (tid & 7) * 4;
        f32x4 acc = {0.f, 0.f, 0.f, 0.f};
        for (int k = 0; k < SD; ++k) {
            const float p = sPp[i * 68 + k];
            const f32x4 h4 = *(const f32x4*)&sHt[k * 36 + j0];
            acc.x = fmaf(p, h4.x, acc.x);
            acc.y = fmaf(p, h4.y, acc.y);
            acc.z = fmaf(p, h4.z, acc.z);
            acc.w = fmaf(p, h4.w, acc.w);
        }
        *(f32x4*)&sA[i * 36 + j0] = acc;
    }
    __syncthreads();

    // ---- S = H @ A + R : one output per thread
    {
        const int i = tid >> 5, j = tid & 31;
        float a = R[i * 32 + j];
        for (int k = 0; k < SD; ++k) a = fmaf(sH[i * 64 + k], sA[k * 36 + j], a);
        sS[i * 33 + j] = a;
    }
    __syncthreads();

    // ---- S^{-1} via Gauss-Jordan on wave 0, lane l owns aug column l of [S|I]
    if (tid < 64) {
        float col[MD];
#pragma unroll
        for (int i = 0; i < MD; ++i)
            col[i] = (tid < MD) ? sS[i * 33 + tid] : ((i == tid - MD) ? 1.f : 0.f);
#pragma unroll
        for (int kp = 0; kp < MD; ++kp) {
            const float piv = __shfl(col[kp], kp);
            const float r = 1.0f / piv;
            col[kp] *= r;                 // scale pivot row
            const float pr = col[kp];
#pragma unroll
            for (int i = 0; i < MD; ++i) {
                if (i == kp) continue;
                const float f = __shfl(col[i], kp);   // aug[i][kp] (pre-update)
                col[i] = fmaf(-f, pr, col[i]);
            }
        }
        if (tid >= MD) {
            const int j = tid - MD;
#pragma unroll
            for (int i = 0; i < MD; ++i) sSi[i * 36 + j] = col[i];
        }
    }
    __syncthreads();

    // ---- K = A @ S^{-1} (tid<512); write LDS (for b) + TRANSPOSED global
    if (tid < 512) {
        const int i = tid >> 3, j0 = (tid & 7) * 4;
        f32x4 acc = {0.f, 0.f, 0.f, 0.f};
        for (int k = 0; k < MD; ++k) {
            const float a = sA[i * 36 + k];
            const f32x4 s4 = *(const f32x4*)&sSi[k * 36 + j0];
            acc.x = fmaf(a, s4.x, acc.x);
            acc.y = fmaf(a, s4.y, acc.y);
            acc.z = fmaf(a, s4.z, acc.z);
            acc.w = fmaf(a, s4.w, acc.w);
        }
        *(f32x4*)&sK[i * 36 + j0] = acc;
        g_Kt[(j0 + 0) * SD + i] = acc.x;
        g_Kt[(j0 + 1) * SD + i] = acc.y;
        g_Kt[(j0 + 2) * SD + i] = acc.z;
        g_Kt[(j0 + 3) * SD + i] = acc.w;
    }
    __syncthreads();

    // ---- b = x_pred - K @ Hx
    if (tid < SD) {
        float a = sxp[tid];
        for (int j = 0; j < MD; ++j) a = fmaf(-sK[tid * 36 + j], sHx[j], a);
        g_b[tid] = a;
    }
}

// ---------------------------------------------------------------------------
// Kernel B v5: j-streaming accumulators.
// Diagnosis (rounds 0-4): all burst-structured variants pin at ~2.4 TB/s.
// Little's law: 6.5 TB/s needs ~9.5 KB reads in flight per CU continuously;
// the {32-load burst -> 16k-cycle pure-VALU body} averages ~1.5 KB (loads
// outstanding ~6% of wave lifetime) -> predicted ~2.4 TB/s = measured.
// Fix: invert loops. Block = 4 waves; wave w owns rows i in [16w,16w+16)
// (acc[16] f32x4 = 64 VGPR). Stream z row-by-row with distance-2 rolling
// prefetch (named regs, static indices): one 1 KiB load per ~128 compute
// cycles for the wave's entire lifetime -> continuous read stream.
// K via g_Kt: 16 consecutive floats per (wave,j) -> merged s_load, scalar-
// cache resident. z loads PLAIN (4 waves/block share rows -> L2 reuse).
// ---------------------------------------------------------------------------
__global__ __launch_bounds__(256) void akf_apply(
    const float* __restrict__ z, float* __restrict__ out, int N)
{
    const int lane = threadIdx.x & 63;
    const int wave = threadIdx.x >> 6;          // 0..3
    const int i0   = wave * 16;                 // first of this wave's 16 rows
    const int c    = blockIdx.x * 256 + lane * 4;
    if (c >= N) return;

    f32x4 acc[16];
#pragma unroll
    for (int r = 0; r < 16; ++r) {
        const float bi = g_b[i0 + r];           // uniform -> s_load
        acc[r] = (f32x4){bi, bi, bi, bi};
    }

    const float* zc = z + c;
    // distance-2 rolling prefetch (named regs only: rule #20)
    f32x4 zA = *(const f32x4*)(zc + (size_t)0 * N);
    f32x4 zB = *(const f32x4*)(zc + (size_t)1 * N);

#pragma unroll 1   // keep the rolling structure: full unroll would re-hoist
    for (int j = 0; j < MD; j += 2) {
        const int jn0 = (j + 2 < MD) ? j + 2 : MD - 2;   // clamped: always valid
        const int jn1 = (j + 3 < MD) ? j + 3 : MD - 1;
        const f32x4 zC = *(const f32x4*)(zc + (size_t)jn0 * N);
        const f32x4 zD = *(const f32x4*)(zc + (size_t)jn1 * N);

        const float* kt0 = &g_Kt[(j + 0) * SD + i0];   // 16 consecutive floats
        const float* kt1 = &g_Kt[(j + 1) * SD + i0];   // -> merged s_loads
#pragma unroll
        for (int r = 0; r < 16; ++r) {
            const float k0 = kt0[r];
            acc[r].x = fmaf(k0, zA.x, acc[r].x);
            acc[r].y = fmaf(k0, zA.y, acc[r].y);
            acc[r].z = fmaf(k0, zA.z, acc[r].z);
            acc[r].w = fmaf(k0, zA.w, acc[r].w);
        }
#pragma unroll
        for (int r = 0; r < 16; ++r) {
            const float k1 = kt1[r];
            acc[r].x = fmaf(k1, zB.x, acc[r].x);
            acc[r].y = fmaf(k1, zB.y, acc[r].y);
            acc[r].z = fmaf(k1, zB.z, acc[r].z);
            acc[r].w = fmaf(k1, zB.w, acc[r].w);
        }
        zA = zC;
        zB = zD;
    }

    float* oc = out + c;
#pragma unroll
    for (int r = 0; r < 16; ++r)
        *(f32x4*)(oc + (size_t)(i0 + r) * N) = acc[r];
}

extern "C" void kernel_launch(void* const* d_in, const int* in_sizes, int n_in,
                              void* d_out, int out_size, void* d_ws, size_t ws_size,
                              hipStream_t stream)
{
    // setup_inputs order: z, F, H, Q, R, P, x  (all float32)
    const float* z = (const float*)d_in[0];
    const float* F = (const float*)d_in[1];
    const float* H = (const float*)d_in[2];
    const float* Q = (const float*)d_in[3];
    const float* R = (const float*)d_in[4];
    const float* P = (const float*)d_in[5];
    const float* x = (const float*)d_in[6];
    float* out = (float*)d_out;
    (void)d_ws; (void)ws_size;   // ws unused (poison fill is unconditional anyway)

    const int N = in_sizes[0] / MD;   // 1048576

    akf_prepare<<<1, 1024, 0, stream>>>(F, H, Q, R, P, x);

    const int cols_per_block = 256;   // 64 lanes x f32x4; rows split across 4 waves
    const int nblocks = (N + cols_per_block - 1) / cols_per_block;   // 4096
    akf_apply<<<nblocks, 256, 0, stream>>>(z, out, N);
}

// Round 6
// 449.184 us; speedup vs baseline: 1.0861x; 1.0861x over previous
//
#include <hip/hip_runtime.h>

#define SD 64   // STATE_DIM
#define MD 32   // MEASURE_DIM

typedef float f32x4 __attribute__((ext_vector_type(4)));

// Static device storage for the prepare->apply handoff.
// g_Kt[j*64+i] = K[i][j] (transposed: 8 consecutive floats per (j, row-group)
// -> one merged s_load_dwordx8 in apply). g_b = b. Rewritten every launch.
__device__ float g_Kt[MD * SD];
__device__ float g_b[SD];

// ---------------------------------------------------------------------------
// Kernel A: one block, 1024 threads. Computes K [64x32] and b [64]:
//   x_new = b + K @ z,  b = x_pred - K @ (H @ x_pred)
// (verified rounds 0-5; unchanged)
// ---------------------------------------------------------------------------
__global__ __launch_bounds__(1024) void akf_prepare(
    const float* __restrict__ F, const float* __restrict__ H,
    const float* __restrict__ Q, const float* __restrict__ R,
    const float* __restrict__ P, const float* __restrict__ x)
{
    __shared__ __align__(16) float sF [SD * SD];    // F row-major (broadcast reads)
    __shared__ __align__(16) float sFt[SD * 68];    // sFt[k*68+j] = F[j][k]
    __shared__ __align__(16) float sP [SD * SD];    // P row-major
    __shared__ __align__(16) float sT [SD * 68];    // T = F@P
    __shared__ __align__(16) float sPp[SD * 68];    // P_pred
    __shared__ __align__(16) float sH [MD * SD];    // H row-major (broadcast reads)
    __shared__ __align__(16) float sHt[SD * 36];    // sHt[k*36+j] = H[j][k]
    __shared__ __align__(16) float sA [SD * 36];    // A = P_pred @ H^T
    __shared__ __align__(16) float sS [MD * 33];    // S
    __shared__ __align__(16) float sSi[MD * 36];    // S^{-1}
    __shared__ __align__(16) float sK [SD * 36];    // K
    __shared__ float sx[SD], sxp[SD], sHx[MD];

    const int tid = threadIdx.x;

    for (int idx = tid; idx < SD * SD; idx += 1024) {
        float f = F[idx], p = P[idx];
        int i = idx >> 6, j = idx & 63;
        sF[idx] = f;
        sFt[j * 68 + i] = f;
        sP[idx] = p;
    }
    for (int idx = tid; idx < MD * SD; idx += 1024) {
        float h = H[idx];
        int j = idx >> 6, k = idx & 63;
        sH[idx] = h;
        sHt[k * 36 + j] = h;
    }
    if (tid < SD) sx[tid] = x[tid];
    __syncthreads();

    // ---- x_pred = F @ x
    if (tid < SD) {
        float a = 0.f;
        for (int k = 0; k < SD; ++k) a = fmaf(sFt[k * 68 + tid], sx[k], a);
        sxp[tid] = a;
    }

    // ---- T = F @ P
    {
        const int i = tid >> 4, j0 = (tid & 15) * 4;
        f32x4 acc = {0.f, 0.f, 0.f, 0.f};
        for (int k = 0; k < SD; ++k) {
            const float f = sF[i * 64 + k];
            const f32x4 p4 = *(const f32x4*)&sP[k * 64 + j0];
            acc.x = fmaf(f, p4.x, acc.x);
            acc.y = fmaf(f, p4.y, acc.y);
            acc.z = fmaf(f, p4.z, acc.z);
            acc.w = fmaf(f, p4.w, acc.w);
        }
        *(f32x4*)&sT[i * 68 + j0] = acc;
    }
    __syncthreads();

    // ---- P_pred = T @ F^T + Q
    {
        const int i = tid >> 4, j0 = (tid & 15) * 4;
        f32x4 acc = *(const f32x4*)&Q[i * 64 + j0];
        for (int k = 0; k < SD; ++k) {
            const float t = sT[i * 68 + k];
            const f32x4 f4 = *(const f32x4*)&sFt[k * 68 + j0];
            acc.x = fmaf(t, f4.x, acc.x);
            acc.y = fmaf(t, f4.y, acc.y);
            acc.z = fmaf(t, f4.z, acc.z);
            acc.w = fmaf(t, f4.w, acc.w);
        }
        *(f32x4*)&sPp[i * 68 + j0] = acc;
    }
    __syncthreads();

    // ---- Hx = H @ x_pred and A = P_pred @ H^T
    if (tid < MD) {
        float a = 0.f;
        for (int k = 0; k < SD; ++k) a = fmaf(sHt[k * 36 + tid], sxp[k], a);
        sHx[tid] = a;
    }
    if (tid < 512) {
        const int i = tid >> 3, j0 = (tid & 7) * 4;
        f32x4 acc = {0.f, 0.f, 0.f, 0.f};
        for (int k = 0; k < SD; ++k) {
            const float p = sPp[i * 68 + k];
            const f32x4 h4 = *(const f32x4*)&sHt[k * 36 + j0];
            acc.x = fmaf(p, h4.x, acc.x);
            acc.y = fmaf(p, h4.y, acc.y);
            acc.z = fmaf(p, h4.z, acc.z);
            acc.w = fmaf(p, h4.w, acc.w);
        }
        *(f32x4*)&sA[i * 36 + j0] = acc;
    }
    __syncthreads();

    // ---- S = H @ A + R
    {
        const int i = tid >> 5, j = tid & 31;
        float a = R[i * 32 + j];
        for (int k = 0; k < SD; ++k) a = fmaf(sH[i * 64 + k], sA[k * 36 + j], a);
        sS[i * 33 + j] = a;
    }
    __syncthreads();

    // ---- S^{-1} via Gauss-Jordan on wave 0
    if (tid < 64) {
        float col[MD];
#pragma unroll
        for (int i = 0; i < MD; ++i)
            col[i] = (tid < MD) ? sS[i * 33 + tid] : ((i == tid - MD) ? 1.f : 0.f);
#pragma unroll
        for (int kp = 0; kp < MD; ++kp) {
            const float piv = __shfl(col[kp], kp);
            const float r = 1.0f / piv;
            col[kp] *= r;
            const float pr = col[kp];
#pragma unroll
            for (int i = 0; i < MD; ++i) {
                if (i == kp) continue;
                const float f = __shfl(col[i], kp);
                col[i] = fmaf(-f, pr, col[i]);
            }
        }
        if (tid >= MD) {
            const int j = tid - MD;
#pragma unroll
            for (int i = 0; i < MD; ++i) sSi[i * 36 + j] = col[i];
        }
    }
    __syncthreads();

    // ---- K = A @ S^{-1}; write LDS (for b) + TRANSPOSED global
    if (tid < 512) {
        const int i = tid >> 3, j0 = (tid & 7) * 4;
        f32x4 acc = {0.f, 0.f, 0.f, 0.f};
        for (int k = 0; k < MD; ++k) {
            const float a = sA[i * 36 + k];
            const f32x4 s4 = *(const f32x4*)&sSi[k * 36 + j0];
            acc.x = fmaf(a, s4.x, acc.x);
            acc.y = fmaf(a, s4.y, acc.y);
            acc.z = fmaf(a, s4.z, acc.z);
            acc.w = fmaf(a, s4.w, acc.w);
        }
        *(f32x4*)&sK[i * 36 + j0] = acc;
        g_Kt[(j0 + 0) * SD + i] = acc.x;
        g_Kt[(j0 + 1) * SD + i] = acc.y;
        g_Kt[(j0 + 2) * SD + i] = acc.z;
        g_Kt[(j0 + 3) * SD + i] = acc.w;
    }
    __syncthreads();

    // ---- b = x_pred - K @ Hx
    if (tid < SD) {
        float a = sxp[tid];
        for (int j = 0; j < MD; ++j) a = fmaf(-sK[tid * 36 + j], sHx[j], a);
        g_b[tid] = a;
    }
}

// ---------------------------------------------------------------------------
// Kernel B v6: T3/T4-style LDS double-buffered pipeline.
// Diagnosis: v4 (~107 us, 3.1 TB/s) = deep bursts but reads/writes never
// overlap; v5 (192 us) = continuous but only 2 loads in flight. Fix: stage z
// tiles into LDS via async global_load_lds (fire-and-forget, no VGPR cost),
// double-buffered, with RAW s_barrier + counted vmcnt (never 0) so tile t+1's
// 32 KB of reads stay in flight across tile t's whole compute+store phase.
// (__syncthreads would emit vmcnt(0)-drain before s_barrier = the m97 stall.)
//
// Per-wave vmcnt ledger (stage = 8 global_load_lds, compute = 16 stores;
// both count in vmcnt, issue order = oldest first):
//   prologue: [L0 x8]
//   t=0: +[L1 x8] -> wait vmcnt(8)   : newest 8 = L1, so L0 done.
//   t=1: +[L2 x8] -> wait vmcnt(24)  : newest 24 = S0(16)+L2(8), L1 done.
//   t=2: +[L3 x8] -> wait vmcnt(24)  : newest 24 = S1(16)+L3(8), L2 done.
//   t=3: (no stage) -> wait vmcnt(16): newest 16 = S2, L3 done.
// Trailing lgkmcnt(0)+barrier per tile: no wave re-stages a buffer another
// wave is still ds_reading.
//
// Geometry: 1024 blocks x 256 thr; block = 4 tiles x 256 cols. LDS = 2x32x256
// f32 = 64 KB -> 2 blocks/CU (two independent pipelines per CU). Wave w
// stages rows [8w,8w+8) and computes out rows [16w,16w+16) in 2 groups of 8
// (acc[8] f32x4 = 32 VGPR). K via g_Kt: s_load_dwordx8 per (j,group).
// Floor: (66 MB HBM-fetch after L3 + 268 MB write) / 6.5 TB/s ~ 51 us.
// ---------------------------------------------------------------------------
#define CT    256   // columns per tile (floats); 1 KB per z-row per tile
#define TILES 4     // tiles per block

__global__ __launch_bounds__(256) void akf_apply(
    const float* __restrict__ z, float* __restrict__ out, int N)
{
    __shared__ __align__(16) float sZ[2][MD][CT];   // 64 KB, double-buffered

    const int lane = threadIdx.x & 63;
    const int w    = threadIdx.x >> 6;          // wave 0..3
    const int colb = lane * 4;
    const int base = blockIdx.x * (CT * TILES);

    if (base + CT * TILES <= N) {
        // ---------------- fast path (always taken when N % 1024 == 0) ------
        // stage: wave w loads rows [8w, 8w+8), 1 KB per row, linear LDS dest
        // (global_load_lds: per-lane GLOBAL addr, wave-uniform LDS base).
        auto stage = [&](int buf, int tc) {
#pragma unroll
            for (int k = 0; k < 8; ++k) {
                const int j = w * 8 + k;
                __builtin_amdgcn_global_load_lds(
                    (const __attribute__((address_space(1))) unsigned int*)
                        (z + (size_t)j * N + tc + colb),
                    (__attribute__((address_space(3))) unsigned int*)
                        &sZ[buf][j][0],
                    16, 0, 0);
            }
        };

        stage(0, base);

#pragma unroll
        for (int t = 0; t < TILES; ++t) {
            const int buf = t & 1;
            if (t + 1 < TILES) stage(buf ^ 1, base + (t + 1) * CT);

            if (t == 0)
                asm volatile("s_waitcnt vmcnt(8)" ::: "memory");
            else if (t + 1 < TILES)
                asm volatile("s_waitcnt vmcnt(24)" ::: "memory");
            else
                asm volatile("s_waitcnt vmcnt(16)" ::: "memory");
            __builtin_amdgcn_s_barrier();
            asm volatile("" ::: "memory");

            const int tc = base + t * CT;
#pragma unroll
            for (int rg = 0; rg < 2; ++rg) {
                const int i0 = w * 16 + rg * 8;
                f32x4 acc[8];
#pragma unroll
                for (int r = 0; r < 8; ++r) {
                    const float bi = g_b[i0 + r];       // uniform -> s_load
                    acc[r] = (f32x4){bi, bi, bi, bi};
                }
#pragma unroll 4
                for (int j = 0; j < MD; ++j) {
                    const f32x4 zj = *(const f32x4*)&sZ[buf][j][colb]; // ds_read_b128
                    const float* kt = &g_Kt[j * SD + i0];  // 8 consec -> s_load_dwordx8
#pragma unroll
                    for (int r = 0; r < 8; ++r) {
                        acc[r].x = fmaf(kt[r], zj.x, acc[r].x);
                        acc[r].y = fmaf(kt[r], zj.y, acc[r].y);
                        acc[r].z = fmaf(kt[r], zj.z, acc[r].z);
                        acc[r].w = fmaf(kt[r], zj.w, acc[r].w);
                    }
                }
#pragma unroll
                for (int r = 0; r < 8; ++r)
                    *(f32x4*)(out + (size_t)(i0 + r) * N + tc + colb) = acc[r];
            }

            asm volatile("s_waitcnt lgkmcnt(0)" ::: "memory");
            __builtin_amdgcn_s_barrier();
            asm volatile("" ::: "memory");
        }
    } else {
        // ---------------- guarded tail path (block-uniform branch; never
        // taken at N = 2^20, kept for shape robustness; perf irrelevant) ----
        for (int c = base + (int)threadIdx.x; c < N; c += 256) {
            float zc[MD];
#pragma unroll
            for (int j = 0; j < MD; ++j) zc[j] = z[(size_t)j * N + c];
#pragma unroll 4
            for (int i = 0; i < SD; ++i) {
                float s = g_b[i];
#pragma unroll
                for (int j = 0; j < MD; ++j) s = fmaf(g_Kt[j * SD + i], zc[j], s);
                out[(size_t)i * N + c] = s;
            }
        }
    }
}

extern "C" void kernel_launch(void* const* d_in, const int* in_sizes, int n_in,
                              void* d_out, int out_size, void* d_ws, size_t ws_size,
                              hipStream_t stream)
{
    // setup_inputs order: z, F, H, Q, R, P, x  (all float32)
    const float* z = (const float*)d_in[0];
    const float* F = (const float*)d_in[1];
    const float* H = (const float*)d_in[2];
    const float* Q = (const float*)d_in[3];
    const float* R = (const float*)d_in[4];
    const float* P = (const float*)d_in[5];
    const float* x = (const float*)d_in[6];
    float* out = (float*)d_out;
    (void)d_ws; (void)ws_size;   // ws unused (its poison fill is unconditional)

    const int N = in_sizes[0] / MD;   // 1048576

    akf_prepare<<<1, 1024, 0, stream>>>(F, H, Q, R, P, x);

    const int cols_per_block = CT * TILES;   // 1024
    const int nblocks = (N + cols_per_block - 1) / cols_per_block;   // 1024
    akf_apply<<<nblocks, 256, 0, stream>>>(z, out, N);
}